// Round 4
// baseline (97.680 us; speedup 1.0000x reference)
//
#include <hip/hip_runtime.h>

#define IMG_H 1080
#define IMG_W 1920
#define TILE_W 128
#define TILE_H 8
#define GXB (IMG_W / TILE_W)   // 15
#define GYB (IMG_H / TILE_H)   // 135
#define BAND_H 14              // rows y0-3 .. y0+10
#define BAND_W 136             // cols gx0-4 .. gx0+131
#define BAND_P 15              // odd column pitch -> conflict-free stride-15 access

// Nonzero iff the 16-bit circular mask has 9 consecutive set bits.
// (Validated absmax=0 in prior rounds; unchanged.)
__device__ __forceinline__ unsigned det9(unsigned m) {
    unsigned x = m | (m << 16);
    unsigned t = x & (x >> 1);   // run 2
    t &= t >> 2;                 // run 4
    t &= t >> 4;                 // run 8
    t &= x >> 8;                 // run 9
    return t;
}

// m = (m << 1) | (val CMP thr) in exactly 2 VALU (v_cmp + v_addc m+m+carry).
#define STEP_GE(m, sc, val, thr)                                          \
    asm("v_cmp_ge_f32 %1, %2, %3\n\tv_addc_co_u32 %0, %1, %0, %0, %1"     \
        : "+v"(m), "=s"(sc) : "v"(val), "v"(thr))
#define STEP_LE(m, sc, val, thr)                                          \
    asm("v_cmp_le_f32 %1, %2, %3\n\tv_addc_co_u32 %0, %1, %0, %0, %1"     \
        : "+v"(m), "=s"(sc) : "v"(val), "v"(thr))

__global__ __launch_bounds__(256) void fast_score_kernel(const float* __restrict__ img,
                                                         float* __restrict__ out) {
    __shared__ float bandT[BAND_W][BAND_P];   // 8160 B, column-major (transposed)

    // Bijective XCD swizzle (m204 form) — keeps y-neighbor blocks on one XCD
    // so the 6-row vertical halo re-reads hit that XCD's L2.
    int bid = blockIdx.x;
    {
        const int nwg = gridDim.x;
        const int q = nwg >> 3, r = nwg & 7;
        const int xcd = bid & 7, idx = bid >> 3;
        bid = (xcd < r ? xcd * (q + 1) : r * (q + 1) + (xcd - r) * q) + idx;
    }
    const int bx = bid % GXB;
    const int t0 = bid / GXB;
    const int by = t0 % GYB;
    const int n  = t0 / GYB;

    const int tx  = threadIdx.x;               // 0..127
    const int ty  = threadIdx.y;               // 0..1
    const int tid = ty * TILE_W + tx;          // 0..255

    const int gx0 = bx * TILE_W;
    const int y0  = by * TILE_H;

    const float* base = img + (size_t)n * (IMG_H * IMG_W);

    // ---- stage 136 cols x 14 rows into transposed LDS (replicate-clamped) ----
    // Row-pair chunks: 136*7 = 952 iters; global reads coalesced (consecutive c),
    // LDS writes stride-15 dwords (conflict-free), pairs merge to ds_write2_b32.
    for (int i = tid; i < BAND_W * (BAND_H / 2); i += 256) {
        const int rp = i / BAND_W;             // 0..6
        const int c  = i - rp * BAND_W;        // 0..135
        const int r0 = rp * 2;
        const int cg  = min(max(gx0 - 4 + c, 0), IMG_W - 1);
        const int ry0 = min(max(y0 - 3 + r0, 0), IMG_H - 1);
        const int ry1 = min(max(y0 - 2 + r0, 0), IMG_H - 1);
        const float v0 = base[(size_t)ry0 * IMG_W + cg];
        const float v1 = base[(size_t)ry1 * IMG_W + cg];
        bandT[c][r0]     = v0;
        bandT[c][r0 + 1] = v1;
    }
    __syncthreads();

    const int cx = tx + 4;     // band col of this thread's pixel column
    const int w0 = ty * 4;     // first window row (wave-uniform)

    // Per-column base pointers (single VGPR base each -> ds_read2_b32 pairing).
    const float* cm3 = &bandT[cx - 3][w0];
    const float* cm2 = &bandT[cx - 2][w0];
    const float* cm1 = &bandT[cx - 1][w0];
    const float* cc0 = &bandT[cx    ][w0];
    const float* cp1 = &bandT[cx + 1][w0];
    const float* cp2 = &bandT[cx + 2][w0];
    const float* cp3 = &bandT[cx + 3][w0];

    // ---- per-thread register window: 54 distinct taps for 4 vertical pixels ----
    float win[7][10];
#pragma unroll
    for (int r = 2; r <= 7; ++r) {             // dx = +-3: rels 2..7
        win[0][r] = cm3[r];
        win[6][r] = cp3[r];
    }
#pragma unroll
    for (int r = 1; r <= 8; ++r) {             // dx = +-2: rels 1..8
        win[1][r] = cm2[r];
        win[5][r] = cp2[r];
    }
#pragma unroll
    for (int r = 0; r <= 3; ++r) {             // dx = +-1: rels 0..3 and 6..9
        win[2][r]     = cm1[r];
        win[4][r]     = cp1[r];
        win[2][r + 6] = cm1[r + 6];
        win[4][r + 6] = cp1[r + 6];
    }
#pragma unroll
    for (int r = 0; r <= 9; ++r) {             // dx = 0: rels 0..9 (incl. centers)
        win[3][r] = cc0[r];
    }

    constexpr int DY[16] = {0, 1, 2, 3, 3, 3, 2, 1, 0, -1, -2, -3, -3, -3, -2, -1};
    constexpr int DX[16] = {-3, -3, -2, -1, 0, 1, 2, 3, 3, 3, 2, 1, 0, -1, -2, -3};

    float* obase = out + ((size_t)n * IMG_H + y0 + w0) * IMG_W + gx0 + tx;

#pragma unroll
    for (int jj = 0; jj < 4; ++jj) {
        const float center = win[3][jj + 3];
        const float hi = center + 20.0f;
        const float lo = center - 20.0f;

        unsigned dark = 0u, bright = 0u;
        unsigned long long sc0, sc1;
#pragma unroll
        for (int k = 0; k < 16; ++k) {
            const float t = win[DX[k] + 3][jj + 3 + DY[k]];   // constant idx after unroll
            STEP_GE(dark,   sc0, t, hi);
            STEP_LE(bright, sc1, t, lo);
        }
        obase[(size_t)jj * IMG_W] = (det9(dark) | det9(bright)) ? 1.0f : 0.0f;
    }
}

extern "C" void kernel_launch(void* const* d_in, const int* in_sizes, int n_in,
                              void* d_out, int out_size, void* d_ws, size_t ws_size,
                              hipStream_t stream) {
    const float* img = (const float*)d_in[0];
    float* out = (float*)d_out;
    const int n_img = in_sizes[0] / (IMG_H * IMG_W);   // = 4
    dim3 grid(GXB * GYB * n_img, 1, 1);                // 8100 blocks
    dim3 block(TILE_W, 2, 1);                          // 256 threads
    fast_score_kernel<<<grid, block, 0, stream>>>(img, out);
}

// Round 5
// 97.525 us; speedup vs baseline: 1.0016x; 1.0016x over previous
//
#include <hip/hip_runtime.h>

#define IMG_H 1080
#define IMG_W 1920
#define TILE_W 128
#define TILE_H 12
#define GXB (IMG_W / TILE_W)    // 15
#define GYB (IMG_H / TILE_H)    // 90
#define BAND_H (TILE_H + 6)     // 18 rows: y0-3 .. y0+14
#define BAND_W 136              // cols gx0-4 .. gx0+131
#define BAND_PW 137             // +1 pad: row-major, conflict-free
#define NCH (BAND_H * (BAND_W / 4))   // 612 float4 chunks

// Nonzero iff the 16-bit circular mask has 9 consecutive set bits.
// (Validated absmax=0 in prior rounds; unchanged.)
__device__ __forceinline__ unsigned det9(unsigned m) {
    unsigned x = m | (m << 16);
    unsigned t = x & (x >> 1);   // run 2
    t &= t >> 2;                 // run 4
    t &= t >> 4;                 // run 8
    t &= x >> 8;                 // run 9
    return t;
}

// m = (m << 1) | (val CMP thr) in exactly 2 VALU (v_cmp + v_addc m+m+carry).
#define STEP_GE(m, sc, val, thr)                                          \
    asm("v_cmp_ge_f32 %1, %2, %3\n\tv_addc_co_u32 %0, %1, %0, %0, %1"     \
        : "+v"(m), "=s"(sc) : "v"(val), "v"(thr))
#define STEP_LE(m, sc, val, thr)                                          \
    asm("v_cmp_le_f32 %1, %2, %3\n\tv_addc_co_u32 %0, %1, %0, %0, %1"     \
        : "+v"(m), "=s"(sc) : "v"(val), "v"(thr))

__global__ __launch_bounds__(256) void fast_score_kernel(const float* __restrict__ img,
                                                         float* __restrict__ out) {
    __shared__ float band[BAND_H][BAND_PW];   // 9864 B

    // Bijective XCD swizzle (m204 form; valid for any nwg).
    int bid = blockIdx.x;
    {
        const int nwg = gridDim.x;
        const int q = nwg >> 3, r = nwg & 7;
        const int xcd = bid & 7, idx = bid >> 3;
        bid = (xcd < r ? xcd * (q + 1) : r * (q + 1) + (xcd - r) * q) + idx;
    }
    const int bx = bid % GXB;
    const int t0 = bid / GXB;
    const int by = t0 % GYB;
    const int n  = t0 / GYB;

    const int tx  = threadIdx.x;               // 0..127
    const int ty  = threadIdx.y;               // 0..1
    const int tid = ty * TILE_W + tx;          // 0..255

    const int gx0 = bx * TILE_W;
    const int y0  = by * TILE_H;

    const float* base = img + (size_t)n * (IMG_H * IMG_W);

    // ---- stage 18x136 band into LDS (replicate-clamped) ----
    if (bx > 0 && bx < GXB - 1) {
        // Interior: 612 aligned float4 chunks; each thread 2-3 chunks.
        // ISSUE-EARLY: all 3 loads independent, issued back-to-back; one
        // latency instead of three serial (addr->load->ds_write) trips.
        const int qa = tid;
        const int qb = tid + 256;
        const bool c_act = tid < (NCH - 512);            // tid < 100
        const int qc = c_act ? tid + 512 : tid;

        const int ra = qa / 34, ca = qa - ra * 34;
        const int rb = qb / 34, cb = qb - rb * 34;
        const int rc = qc / 34, cc = qc - rc * 34;

        const int rya = min(max(y0 - 3 + ra, 0), IMG_H - 1);
        const int ryb = min(max(y0 - 3 + rb, 0), IMG_H - 1);
        const int ryc = min(max(y0 - 3 + rc, 0), IMG_H - 1);

        const float4 va = *(const float4*)(base + (size_t)rya * IMG_W + (gx0 - 4 + ca * 4));
        const float4 vb = *(const float4*)(base + (size_t)ryb * IMG_W + (gx0 - 4 + cb * 4));
        const float4 vc = *(const float4*)(base + (size_t)ryc * IMG_W + (gx0 - 4 + cc * 4));

        *(float4*)&band[ra][ca * 4] = va;
        *(float4*)&band[rb][cb * 4] = vb;
        if (c_act) *(float4*)&band[rc][cc * 4] = vc;
    } else {
        // x-edge blocks (2 of 15): per-element replicate clamp, block-uniform.
        for (int i = tid; i < BAND_H * BAND_W; i += 256) {
            const int r  = i / BAND_W;
            const int c  = i - r * BAND_W;
            const int ry = min(max(y0 - 3 + r, 0), IMG_H - 1);
            const int cg = min(max(gx0 - 4 + c, 0), IMG_W - 1);
            band[r][c] = base[(size_t)ry * IMG_W + cg];
        }
    }
    __syncthreads();

    constexpr int DY[16] = {0, 1, 2, 3, 3, 3, 2, 1, 0, -1, -2, -3, -3, -3, -2, -1};
    constexpr int DX[16] = {-3, -3, -2, -1, 0, 1, 2, 3, 3, 3, 2, 1, 0, -1, -2, -3};

    const int cx = tx + 4;       // band col of this thread's pixel column
    const int w0 = ty * (TILE_H / 2);   // 0 or 6: first pixel row within tile

    float* obase = out + ((size_t)n * IMG_H + y0 + w0) * IMG_W + gx0 + tx;

#pragma unroll
    for (int jj = 0; jj < TILE_H / 2; ++jj) {      // 6 vertical pixels per thread
        const int rr = w0 + jj + 3;                // band row of the center

        const float center = band[rr][cx];
        const float hi = center + 20.0f;
        const float lo = center - 20.0f;

        unsigned dark = 0u, bright = 0u;
        unsigned long long sc0, sc1;
#pragma unroll
        for (int k = 0; k < 16; ++k) {
            const float t = band[rr + DY[k]][cx + DX[k]];  // const offsets after unroll
            STEP_GE(dark,   sc0, t, hi);
            STEP_LE(bright, sc1, t, lo);
        }
        obase[(size_t)jj * IMG_W] = (det9(dark) | det9(bright)) ? 1.0f : 0.0f;
    }
}

extern "C" void kernel_launch(void* const* d_in, const int* in_sizes, int n_in,
                              void* d_out, int out_size, void* d_ws, size_t ws_size,
                              hipStream_t stream) {
    const float* img = (const float*)d_in[0];
    float* out = (float*)d_out;
    const int n_img = in_sizes[0] / (IMG_H * IMG_W);   // = 4
    dim3 grid(GXB * GYB * n_img, 1, 1);                // 5400 blocks
    dim3 block(TILE_W, 2, 1);                          // 256 threads
    fast_score_kernel<<<grid, block, 0, stream>>>(img, out);
}